// Round 2
// baseline (332.386 us; speedup 1.0000x reference)
//
#include <hip/hip_runtime.h>
#include <hip/hip_bf16.h>
#include <cstdint>

// Problem constants (fixed by setup_inputs)
#define B_    32
#define T_    4096
#define C_    256
#define NOUT  512   // GEMM N: 256 value + 256 gate
#define BM    64    // rows (time steps) per block
#define DMAX  16    // max supported dilation (problem uses 4)

typedef __attribute__((ext_vector_type(8))) short bf16x8;
typedef __attribute__((ext_vector_type(4))) float f32x4;
typedef __attribute__((ext_vector_type(4))) short s16x4;

static __device__ __forceinline__ short f2bf(float f) {
  union { float f; uint32_t u; } v; v.f = f;
  uint32_t u = v.u;
  return (short)((u + 0x7fffu + ((u >> 16) & 1u)) >> 16);  // RNE
}

// ---------------------------------------------------------------------------
// Prep: bf16 weight image arranged for DIRECT per-lane fragment loads:
//   wimg[ks*16384 + n*32 + kk]  (shorts), kk = k within k-step (0..31)
// Lane (row15,qw) of a wave reads 16B at n=(base+row15), kk=qw*8 → a wave's
// fragment read covers 1024 contiguous bytes (16 cache lines), fully coalesced.
// n<256 -> value feature (Wv), n>=256 -> gate (Wg). k<256 -> tap0, else tap1.
// ---------------------------------------------------------------------------
__global__ void prep_weights(const float* __restrict__ Wv, const float* __restrict__ Wg,
                             const float* __restrict__ bv, const float* __restrict__ bg,
                             short* __restrict__ wimg, float* __restrict__ bcat) {
  int id = blockIdx.x * 256 + threadIdx.x;   // 16*512*32 = 262144 total
  int kk = id & 31;
  int n  = (id >> 5) & 511;
  int ks = id >> 14;
  int k  = ks * 32 + kk;
  int tap = k >> 8, kr = k & 255;
  int sel = n >> 8, f = n & 255;
  const float* W = sel ? Wg : Wv;
  wimg[id] = f2bf(W[((size_t)tap * 256 + kr) * 256 + f]);
  if (id < 512) bcat[id] = (id < 256) ? bv[id] : bg[id - 256];
}

// ---------------------------------------------------------------------------
// Main: one block = 64 time rows of one batch, full N=512. 4 waves split N:
// wave w owns value cols [64w,64w+64) and gate cols [256+64w, ...) so v/g
// pairs share a lane for the fused epilogue. K-loop is BARRIER-FREE:
// x-tile staged once in LDS; weight fragments load straight from L2 to VGPRs.
// ---------------------------------------------------------------------------
__global__ __launch_bounds__(256, 3) void snail_main(
    const float* __restrict__ x, const short* __restrict__ wimg,
    const float* __restrict__ bcat, const int* __restrict__ dptr,
    float* __restrict__ out) {
  __shared__ __align__(16) short lx[(BM + DMAX) * C_];  // 40 KiB, swizzled bf16 x-tile

  const int d    = *dptr;
  const int bid  = blockIdx.x;
  const int b    = bid >> 6;        // T_/BM = 64 tiles per batch
  const int t0   = (bid & 63) * BM;
  const int tid  = threadIdx.x;
  const int lane = tid & 63;
  const int w    = tid >> 6;
  const int row15 = lane & 15;
  const int qw    = lane >> 4;      // quarter-wave 0..3

  const float* xb = x + (size_t)b * T_ * C_;

  // ---- stage X rows t0-d .. t0+BM-1 into LDS rows 0..BM+d-1 (bf16, swizzled)
  const int nrows = BM + d;
  for (int i = tid; i < nrows * 64; i += 256) {
    int r = i >> 6, c4 = i & 63;
    int t = t0 - d + r;
    float4 v = make_float4(0.f, 0.f, 0.f, 0.f);
    if (t >= 0) v = *(const float4*)(xb + (size_t)t * C_ + c4 * 4);
    s16x4 s;
    s.x = f2bf(v.x); s.y = f2bf(v.y); s.z = f2bf(v.z); s.w = f2bf(v.w);
    int byte = (r * 512 + c4 * 8) ^ ((r & 7) << 4);
    *(s16x4*)((char*)lx + byte) = s;
  }
  __syncthreads();   // the ONLY barrier

  f32x4 accv[4][4], accg[4][4];
#pragma unroll
  for (int mi = 0; mi < 4; ++mi)
#pragma unroll
    for (int ni = 0; ni < 4; ++ni) {
      accv[mi][ni] = (f32x4){0.f, 0.f, 0.f, 0.f};
      accg[mi][ni] = (f32x4){0.f, 0.f, 0.f, 0.f};
    }

  // per-lane weight base: n = w*64 + row15 (ni adds 16n = 512 shorts), kk = qw*8
  const short* wl = wimg + (size_t)(w * 64 + row15) * 32 + qw * 8;

  for (int ks = 0; ks < 16; ++ks) {
    const short* wk = wl + ks * 16384;

    // A fragments: lane holds A[row=16mi+row15+rofs][k=qw*8+j] (swizzled LDS)
    bf16x8 af[4];
    const int rofs = (ks >= 8) ? d : 0;
    const int cb = (ks & 7) * 64 + qw * 16;
#pragma unroll
    for (int mi = 0; mi < 4; ++mi) {
      int r = 16 * mi + row15 + rofs;
      int byte = (r * 512 + cb) ^ ((r & 7) << 4);
      af[mi] = *(const bf16x8*)((const char*)lx + byte);
    }

#pragma unroll
    for (int ni = 0; ni < 4; ++ni) {
      bf16x8 bv_ = *(const bf16x8*)(wk + ni * 512);           // value cols
      bf16x8 bg_ = *(const bf16x8*)(wk + ni * 512 + 8192);    // gate cols (+256n)
#pragma unroll
      for (int mi = 0; mi < 4; ++mi) {
        accv[mi][ni] = __builtin_amdgcn_mfma_f32_16x16x32_bf16(af[mi], bv_, accv[mi][ni], 0, 0, 0);
        accg[mi][ni] = __builtin_amdgcn_mfma_f32_16x16x32_bf16(af[mi], bg_, accg[mi][ni], 0, 0, 0);
      }
    }
  }

  // ---- epilogue: activations = tanh(v+bv) * sigmoid(g+bg)
  float* ob = out + (size_t)b * T_ * NOUT;
#pragma unroll
  for (int ni = 0; ni < 4; ++ni) {
    int f = w * 64 + 16 * ni + row15;
    float biasv = bcat[f], biasg = bcat[256 + f];
#pragma unroll
    for (int mi = 0; mi < 4; ++mi) {
      int rbase = t0 + 16 * mi + qw * 4;   // C/D: row=(lane>>4)*4+j, col=lane&15
      f32x4 v = accv[mi][ni], g = accg[mi][ni];
#pragma unroll
      for (int j = 0; j < 4; ++j) {
        float vv = v[j] + biasv, gg = g[j] + biasg;
        float th = 1.f - 2.f / (__expf(2.f * vv) + 1.f);
        float sg = 1.f / (1.f + __expf(-gg));
        ob[(size_t)(rbase + j) * NOUT + f] = th * sg;
      }
    }
  }

  // ---- exact fp32 passthrough: out[:, :, 256:512] = x (rows L2-hot)
  for (int i = tid; i < BM * 64; i += 256) {
    int r = i >> 6, c4 = i & 63;
    float4 v = *(const float4*)(xb + (size_t)(t0 + r) * C_ + c4 * 4);
    *(float4*)(ob + (size_t)(t0 + r) * NOUT + C_ + c4 * 4) = v;
  }
}

extern "C" void kernel_launch(void* const* d_in, const int* in_sizes, int n_in,
                              void* d_out, int out_size, void* d_ws, size_t ws_size,
                              hipStream_t stream) {
  const float* x  = (const float*)d_in[0];
  const float* Wv = (const float*)d_in[1];
  const float* bv = (const float*)d_in[2];
  const float* Wg = (const float*)d_in[3];
  const float* bg = (const float*)d_in[4];
  const int* dil  = (const int*)d_in[5];
  float* out = (float*)d_out;

  short* wimg = (short*)d_ws;                          // 512 KiB weight image
  float* bcat = (float*)((char*)d_ws + 16 * 32768);    // 2 KiB biases

  prep_weights<<<1024, 256, 0, stream>>>(Wv, Wg, bv, bg, wimg, bcat);
  snail_main<<<B_ * (T_ / BM), 256, 0, stream>>>(x, wimg, bcat, dil, out);
}

// Round 3
// 176.700 us; speedup vs baseline: 1.8811x; 1.8811x over previous
//
#include <hip/hip_runtime.h>
#include <hip/hip_bf16.h>
#include <cstdint>

// Problem constants (fixed by setup_inputs)
#define B_    32
#define T_    4096
#define C_    256
#define NOUT  512   // GEMM N: 256 value + 256 gate
#define BM    128   // rows (time steps) per block
#define DMAX  16    // max supported dilation (problem uses 4)
#define NROWS (BM + DMAX)   // LDS x-tile rows (144)

typedef __attribute__((ext_vector_type(8))) short bf16x8;
typedef __attribute__((ext_vector_type(4))) float f32x4;
typedef __attribute__((ext_vector_type(4))) short s16x4;

static __device__ __forceinline__ short f2bf(float f) {
  union { float f; uint32_t u; } v; v.f = f;
  uint32_t u = v.u;
  return (short)((u + 0x7fffu + ((u >> 16) & 1u)) >> 16);  // RNE
}

// ---------------------------------------------------------------------------
// Prep: bf16 weight image laid out EXACTLY as the per-k-step LDS tile
// (32 KiB per k-step of K=32), XOR-swizzled: byte = (n*64 + kk*2) ^ ((n&7)<<4).
// n in [0,512): n<256 -> value feature f=n (Wv), else gate f=n-256 (Wg).
// k = 32*ks + kk: k<256 -> tap0 (x[t-d]), else tap1 (x[t]).
// ---------------------------------------------------------------------------
__global__ void prep_weights(const float* __restrict__ Wv, const float* __restrict__ Wg,
                             const float* __restrict__ bv, const float* __restrict__ bg,
                             short* __restrict__ wimg, float* __restrict__ bcat) {
  int id = blockIdx.x * 256 + threadIdx.x;     // 16*512*32 = 262144 total
  int f   = id & 255;
  int sel = (id >> 8) & 1;
  int kk  = (id >> 9) & 31;
  int ks  = id >> 14;
  int k   = ks * 32 + kk;
  int tap = k >> 8;
  int kr  = k & 255;
  const float* W = sel ? Wg : Wv;
  float w = W[((size_t)tap * 256 + kr) * 256 + f];
  int n = sel * 256 + f;
  int byte_off = (n * 64 + kk * 2) ^ ((n & 7) << 4);
  wimg[ks * 16384 + (byte_off >> 1)] = f2bf(w);
  if (id < 512) bcat[id] = (id < 256) ? bv[id] : bg[id - 256];
}

// ---------------------------------------------------------------------------
// Main: 512 threads = 8 waves (2M x 4N). Block = 128 time rows, full N=512.
// Wave (wm,wn) computes rows [64wm,64wm+64) x value cols [64wn,+64) and gate
// cols [256+64wn,+64). Weights double-buffered in LDS via the T3-mini 2-phase
// pipeline: STAGE(ks+1) -> compute(ks) -> one __syncthreads (drain overlapped).
// Accumulate TRANSPOSED (weights in A-slot) so the epilogue stores float4.
// ---------------------------------------------------------------------------
__global__ __launch_bounds__(512, 2) void snail_main(
    const float* __restrict__ x, const short* __restrict__ wimg,
    const float* __restrict__ bcat, const int* __restrict__ dptr,
    float* __restrict__ out) {
  __shared__ __align__(16) short lx[NROWS * C_];   // 72 KiB, swizzled bf16 x-tile
  __shared__ __align__(16) short lw[2][16384];     // 2 x 32 KiB weight k-step buffers

  const int d    = *dptr;
  const int bid  = blockIdx.x;
  const int b    = bid >> 5;        // T_/BM = 32 tiles per batch
  const int t0   = (bid & 31) * BM;
  const int tid  = threadIdx.x;
  const int lane = tid & 63;
  const int w    = tid >> 6;
  const int wm   = w >> 2;          // 0..1  (M half)
  const int wn   = w & 3;           // 0..3  (N quarter)
  const int row15 = lane & 15;
  const int qw    = lane >> 4;      // quarter-wave 0..3

  const float* xb = x + (size_t)b * T_ * C_;
  float* ob = out + (size_t)b * T_ * NOUT;

  typedef const __attribute__((address_space(1))) unsigned int* gp_t;
  typedef __attribute__((address_space(3))) unsigned int* lp_t;

  // ---- prologue: issue weight stage for ks=0 (overlaps with x staging below)
  {
    const char* src = (const char*)wimg + tid * 16;
    char* dst = (char*)&lw[0][0] + w * 1024;      // wave-uniform LDS base
#pragma unroll
    for (int c = 0; c < 4; ++c)
      __builtin_amdgcn_global_load_lds((gp_t)(const void*)(src + c * 8192),
                                       (lp_t)(void*)(dst + c * 8192), 16, 0, 0);
  }

  // ---- stage X rows t0-d..t0+BM-1 into LDS (bf16, swizzled) + fused fp32
  //      passthrough out[:, :, 256:512] = x (rows in-register, L2 not needed)
  const int nrows = BM + d;
  for (int i = tid; i < nrows * 64; i += 512) {
    int r = i >> 6, c4 = i & 63;
    int t = t0 - d + r;
    float4 v = make_float4(0.f, 0.f, 0.f, 0.f);
    if (t >= 0) v = *(const float4*)(xb + (size_t)t * C_ + c4 * 4);
    if (r >= d)  // t in [t0, t0+BM)
      *(float4*)(ob + (size_t)t * NOUT + C_ + c4 * 4) = v;
    s16x4 s;
    s.x = f2bf(v.x); s.y = f2bf(v.y); s.z = f2bf(v.z); s.w = f2bf(v.w);
    int byte = (r * 512 + c4 * 8) ^ ((r & 7) << 4);
    *(s16x4*)((char*)lx + byte) = s;
  }
  __syncthreads();   // lx ready, lw[0] ready (full drain, once)

  f32x4 accv[4][4], accg[4][4];
#pragma unroll
  for (int mi = 0; mi < 4; ++mi)
#pragma unroll
    for (int ni = 0; ni < 4; ++ni) {
      accv[mi][ni] = (f32x4){0.f, 0.f, 0.f, 0.f};
      accg[mi][ni] = (f32x4){0.f, 0.f, 0.f, 0.f};
    }

  for (int ks = 0; ks < 16; ++ks) {
    // ---- STAGE next k-step into the other buffer (loads fly during compute)
    if (ks < 15) {
      const char* src = (const char*)wimg + (ks + 1) * 32768 + tid * 16;
      char* dst = (char*)&lw[(ks + 1) & 1][0] + w * 1024;
#pragma unroll
      for (int c = 0; c < 4; ++c)
        __builtin_amdgcn_global_load_lds((gp_t)(const void*)(src + c * 8192),
                                         (lp_t)(void*)(dst + c * 8192), 16, 0, 0);
    }

    // ---- compute current k-step from lw[ks&1]
    const char* lwc = (const char*)&lw[ks & 1][0];

    // A fragments (x): lane holds A[row=64wm+16mi+row15+rofs][k=qw*8+j]
    bf16x8 af[4];
    const int rofs = (ks >= 8) ? d : 0;
    const int cb = (ks & 7) * 64 + qw * 16;
#pragma unroll
    for (int mi = 0; mi < 4; ++mi) {
      int r = 64 * wm + 16 * mi + row15 + rofs;
      int byte = (r * 512 + cb) ^ ((r & 7) << 4);
      af[mi] = *(const bf16x8*)((const char*)lx + byte);
    }
#pragma unroll
    for (int ni = 0; ni < 4; ++ni) {
      int nv = wn * 64 + 16 * ni + row15;
      bf16x8 bv_ = *(const bf16x8*)(lwc + ((nv * 64 + qw * 16) ^ ((nv & 7) << 4)));
      int ng = 256 + nv;
      bf16x8 bg_ = *(const bf16x8*)(lwc + ((ng * 64 + qw * 16) ^ ((ng & 7) << 4)));
#pragma unroll
      for (int mi = 0; mi < 4; ++mi) {
        // TRANSPOSED: weights in A-slot -> D[f][t]; lane holds 4 consecutive f
        accv[mi][ni] = __builtin_amdgcn_mfma_f32_16x16x32_bf16(bv_, af[mi], accv[mi][ni], 0, 0, 0);
        accg[mi][ni] = __builtin_amdgcn_mfma_f32_16x16x32_bf16(bg_, af[mi], accg[mi][ni], 0, 0, 0);
      }
    }
    __syncthreads();   // drains vmcnt: next buffer ready; all reads of lwc done
  }

  // ---- epilogue: out[t][f] = tanh(v+bv)*sigmoid(g+bg), float4 per lane
  //      D^T layout: t = t0+64wm+16mi+row15 ; f = 64wn+16ni+qw*4+j
#pragma unroll
  for (int ni = 0; ni < 4; ++ni) {
    int f0 = wn * 64 + 16 * ni + qw * 4;
    float4 bv4 = *(const float4*)(bcat + f0);
    float4 bg4 = *(const float4*)(bcat + 256 + f0);
#pragma unroll
    for (int mi = 0; mi < 4; ++mi) {
      int t = t0 + 64 * wm + 16 * mi + row15;
      f32x4 v = accv[mi][ni], g = accg[mi][ni];
      float4 res;
      float* rp = &res.x;
      const float* bvp = &bv4.x;
      const float* bgp = &bg4.x;
#pragma unroll
      for (int j = 0; j < 4; ++j) {
        float vv = v[j] + bvp[j], gg = g[j] + bgp[j];
        float th = 1.f - 2.f / (__expf(2.f * vv) + 1.f);
        float sg = 1.f / (1.f + __expf(-gg));
        rp[j] = th * sg;
      }
      *(float4*)(ob + (size_t)t * NOUT + f0) = res;
    }
  }
}

extern "C" void kernel_launch(void* const* d_in, const int* in_sizes, int n_in,
                              void* d_out, int out_size, void* d_ws, size_t ws_size,
                              hipStream_t stream) {
  const float* x  = (const float*)d_in[0];
  const float* Wv = (const float*)d_in[1];
  const float* bv = (const float*)d_in[2];
  const float* Wg = (const float*)d_in[3];
  const float* bg = (const float*)d_in[4];
  const int* dil  = (const int*)d_in[5];
  float* out = (float*)d_out;

  short* wimg = (short*)d_ws;                          // 512 KiB weight image
  float* bcat = (float*)((char*)d_ws + 16 * 32768);    // 2 KiB biases

  prep_weights<<<1024, 256, 0, stream>>>(Wv, Wg, bv, bg, wimg, bcat);
  snail_main<<<B_ * (T_ / BM), 512, 0, stream>>>(x, wimg, bcat, dil, out);
}

// Round 5
// 127.844 us; speedup vs baseline: 2.5999x; 1.3822x over previous
//
#include <hip/hip_runtime.h>
#include <hip/hip_bf16.h>
#include <cstdint>

// Problem constants (fixed by setup_inputs)
#define B_    32
#define T_    4096
#define C_    256
#define BM    64     // time rows per block
#define DMAX  16     // max supported dilation (problem uses 4)
#define NROWS (BM + DMAX)

typedef __attribute__((ext_vector_type(8))) short bf16x8;
typedef __attribute__((ext_vector_type(4))) float f32x4;
typedef __attribute__((ext_vector_type(4))) short s16x4;

static __device__ __forceinline__ short f2bf(float f) {
  union { float f; uint32_t u; } v; v.f = f;
  uint32_t u = v.u;
  return (short)((u + 0x7fffu + ((u >> 16) & 1u)) >> 16);  // RNE
}

// ---------------------------------------------------------------------------
// Prep: bf16 weight image, LINEAR layout for direct per-lane fragment loads:
//   wimg[((nb*16 + ks)*256 + np)*32 + kk]   (shorts)
// nb = N-half (block split), ks = k-step (K=32), np = local col (0..127 value,
// 128..255 gate), kk = k within step. A wave's fragment read (16 lanes x 64B)
// covers 1KB contiguous -> fully coalesced L2 hits.
// k = 32*ks + kk: k<256 -> tap0 (x[t-d]), else tap1 (x[t]).
// ---------------------------------------------------------------------------
__global__ void prep_weights(const float* __restrict__ Wv, const float* __restrict__ Wg,
                             const float* __restrict__ bv, const float* __restrict__ bg,
                             short* __restrict__ wimg, float* __restrict__ bcat) {
  int id = blockIdx.x * 256 + threadIdx.x;   // 2*16*256*32 = 262144 total
  int kk = id & 31;
  int np = (id >> 5) & 255;
  int ks = (id >> 13) & 15;
  int nb = id >> 17;
  int k = ks * 32 + kk, tap = k >> 8, kr = k & 255;
  int sel = np >> 7;                 // 0=value, 1=gate
  int f = nb * 128 + (np & 127);
  const float* W = sel ? Wg : Wv;
  wimg[id] = f2bf(W[((size_t)tap * 256 + kr) * 256 + f]);
  if (id < 512) bcat[id] = (id < 256) ? bv[id] : bg[id - 256];
}

// ---------------------------------------------------------------------------
// Main: 256 threads = 4 waves. Block = 64 time rows x one N-half (128 value +
// 128 gate cols). LDS = 40 KiB x-tile only -> 4 blocks/CU, 16 waves/CU.
// K-loop is BARRIER-FREE: weights load straight from L2 to VGPRs.
// Transposed MFMA (weights in A-slot) -> float4 nontemporal stores.
// ---------------------------------------------------------------------------
__global__ __launch_bounds__(256, 4) void snail_main(
    const float* __restrict__ x, const short* __restrict__ wimg,
    const float* __restrict__ bcat, const int* __restrict__ dptr,
    float* __restrict__ out) {
  __shared__ __align__(16) short lx[NROWS * C_];   // 40 KiB, swizzled bf16 x-tile

  const int d = *dptr;
  // XCD-aware bijective swizzle (4096 blocks, 4096 % 8 == 0)
  const int bid = blockIdx.x;
  const int swz = (bid & 7) * 512 + (bid >> 3);
  const int nb = swz & 1;                 // N-half
  const int t0 = ((swz >> 1) & 63) * BM;  // time tile
  const int b  = swz >> 7;                // batch

  const int tid  = threadIdx.x;
  const int lane = tid & 63;
  const int w    = tid >> 6;
  const int row15 = lane & 15;
  const int qw    = lane >> 4;

  const float* xb = x + (size_t)b * T_ * C_;
  float* ob = out + (size_t)b * T_ * 512;

  // ---- stage x rows t0-d..t0+BM-1 into LDS (bf16, swizzled); fuse the exact
  //      fp32 passthrough for this block's N-half (x rows are in-register).
  for (int i = tid; i < d * 64; i += 256) {          // prefix rows [0,d)
    int r = i >> 6, c4 = i & 63;
    int t = t0 - d + r;
    f32x4 v = (f32x4){0.f, 0.f, 0.f, 0.f};
    if (t >= 0) v = *(const f32x4*)(xb + (size_t)t * C_ + c4 * 4);
    s16x4 s;
    s.x = f2bf(v.x); s.y = f2bf(v.y); s.z = f2bf(v.z); s.w = f2bf(v.w);
    int byte = (r * 512 + c4 * 8) ^ ((r & 7) << 4);
    *(s16x4*)((char*)lx + byte) = s;
  }
#pragma unroll 4
  for (int ii = 0; ii < 16; ++ii) {                  // main rows [d, d+BM)
    int i = ii * 256 + tid;
    int rr = i >> 6, c4 = i & 63;
    int t = t0 + rr, r = rr + d;
    f32x4 v = *(const f32x4*)(xb + (size_t)t * C_ + c4 * 4);
    if ((c4 >> 5) == nb)   // this block's half of the passthrough cols
      __builtin_nontemporal_store(v, (f32x4*)(ob + (size_t)t * 512 + C_ + c4 * 4));
    s16x4 s;
    s.x = f2bf(v.x); s.y = f2bf(v.y); s.z = f2bf(v.z); s.w = f2bf(v.w);
    int byte = (r * 512 + c4 * 8) ^ ((r & 7) << 4);
    *(s16x4*)((char*)lx + byte) = s;
  }
  __syncthreads();   // the ONLY barrier

  f32x4 accv[4][2], accg[4][2];
#pragma unroll
  for (int mi = 0; mi < 4; ++mi)
#pragma unroll
    for (int ni = 0; ni < 2; ++ni) {
      accv[mi][ni] = (f32x4){0.f, 0.f, 0.f, 0.f};
      accg[mi][ni] = (f32x4){0.f, 0.f, 0.f, 0.f};
    }

  // per-lane weight base: np = w*32 + row15 (value), kk = qw*8
  const short* wl = wimg + (size_t)nb * 131072 + (w * 32 + row15) * 32 + qw * 8;

  for (int ks = 0; ks < 16; ++ks) {
    const short* wk = wl + ks * 8192;
    bf16x8 b0 = *(const bf16x8*)(wk);           // value ni=0
    bf16x8 b1 = *(const bf16x8*)(wk + 512);     // value ni=1 (+16 cols)
    bf16x8 g0 = *(const bf16x8*)(wk + 4096);    // gate  ni=0 (+128 cols)
    bf16x8 g1 = *(const bf16x8*)(wk + 4608);    // gate  ni=1

    // A fragments (x): lane holds A[row=16mi+row15+rofs][k=qw*8+j]
    bf16x8 af[4];
    const int rofs = (ks >= 8) ? d : 0;
    const int cb = (ks & 7) * 64 + qw * 16;
#pragma unroll
    for (int mi = 0; mi < 4; ++mi) {
      int r = 16 * mi + row15 + rofs;
      af[mi] = *(const bf16x8*)((const char*)lx + ((r * 512 + cb) ^ ((r & 7) << 4)));
    }
#pragma unroll
    for (int mi = 0; mi < 4; ++mi) {
      // TRANSPOSED: weights in A-slot -> D[f][t]; lane holds 4 consecutive f
      accv[mi][0] = __builtin_amdgcn_mfma_f32_16x16x32_bf16(b0, af[mi], accv[mi][0], 0, 0, 0);
      accv[mi][1] = __builtin_amdgcn_mfma_f32_16x16x32_bf16(b1, af[mi], accv[mi][1], 0, 0, 0);
      accg[mi][0] = __builtin_amdgcn_mfma_f32_16x16x32_bf16(g0, af[mi], accg[mi][0], 0, 0, 0);
      accg[mi][1] = __builtin_amdgcn_mfma_f32_16x16x32_bf16(g1, af[mi], accg[mi][1], 0, 0, 0);
    }
  }

  // ---- epilogue: out[t][f] = tanh(v+bv)*sigmoid(g+bg), float4 nt-stores
  //      D^T layout: t = t0+16mi+row15 ; f = nb*128 + w*32 + 16ni + qw*4 + j
#pragma unroll
  for (int ni = 0; ni < 2; ++ni) {
    int f0 = nb * 128 + w * 32 + 16 * ni + qw * 4;
    f32x4 bv4 = *(const f32x4*)(bcat + f0);
    f32x4 bg4 = *(const f32x4*)(bcat + 256 + f0);
#pragma unroll
    for (int mi = 0; mi < 4; ++mi) {
      int t = t0 + 16 * mi + row15;
      f32x4 v = accv[mi][ni], g = accg[mi][ni];
      f32x4 res;
#pragma unroll
      for (int j = 0; j < 4; ++j) {
        float vv = v[j] + bv4[j], gg = g[j] + bg4[j];
        float th = 1.f - 2.f / (__expf(2.f * vv) + 1.f);
        float sg = 1.f / (1.f + __expf(-gg));
        res[j] = th * sg;
      }
      __builtin_nontemporal_store(res, (f32x4*)(ob + (size_t)t * 512 + f0));
    }
  }
}

extern "C" void kernel_launch(void* const* d_in, const int* in_sizes, int n_in,
                              void* d_out, int out_size, void* d_ws, size_t ws_size,
                              hipStream_t stream) {
  const float* x  = (const float*)d_in[0];
  const float* Wv = (const float*)d_in[1];
  const float* bv = (const float*)d_in[2];
  const float* Wg = (const float*)d_in[3];
  const float* bg = (const float*)d_in[4];
  const int* dil  = (const int*)d_in[5];
  float* out = (float*)d_out;

  short* wimg = (short*)d_ws;                          // 512 KiB weight image
  float* bcat = (float*)((char*)d_ws + 16 * 32768);    // 2 KiB biases

  prep_weights<<<1024, 256, 0, stream>>>(Wv, Wg, bv, bg, wimg, bcat);
  snail_main<<<B_ * (T_ / BM) * 2, 256, 0, stream>>>(x, wimg, bcat, dil, out);
}

// Round 6
// 121.817 us; speedup vs baseline: 2.7286x; 1.0495x over previous
//
#include <hip/hip_runtime.h>
#include <hip/hip_bf16.h>
#include <cstdint>

// Problem constants (fixed by setup_inputs)
#define B_    32
#define T_    4096
#define C_    256
#define BM    64     // time rows per block
#define DMAX  16     // max supported dilation (problem uses 4)
#define NROWS (BM + DMAX)

typedef __attribute__((ext_vector_type(8))) short bf16x8;
typedef __attribute__((ext_vector_type(4))) float f32x4;
typedef __attribute__((ext_vector_type(4))) short s16x4;

static __device__ __forceinline__ short f2bf(float f) {
  // native conversion path -> compiler can emit v_cvt_(pk_)bf16_f32
  __hip_bfloat16 h = __float2bfloat16(f);
  union { __hip_bfloat16 h; short s; } u; u.h = h;
  return u.s;
}

static __device__ __forceinline__ float rcp_(float x) {
  return __builtin_amdgcn_rcpf(x);   // ~2^-22 rel error, 1 instr vs ~12 for fp32 div
}

// ---------------------------------------------------------------------------
// Prep: bf16 weight image, LINEAR layout for direct per-lane fragment loads:
//   wimg[((nb*16 + ks)*256 + np)*32 + kk]   (shorts)
// nb = N-half (block split), ks = k-step (K=32), np = local col (0..127 value,
// 128..255 gate), kk = k within step. A wave's fragment read (16 lanes x 64B)
// covers 1KB contiguous -> fully coalesced L2 hits.
// k = 32*ks + kk: k<256 -> tap0 (x[t-d]), else tap1 (x[t]).
// ---------------------------------------------------------------------------
__global__ void prep_weights(const float* __restrict__ Wv, const float* __restrict__ Wg,
                             const float* __restrict__ bv, const float* __restrict__ bg,
                             short* __restrict__ wimg, float* __restrict__ bcat) {
  int id = blockIdx.x * 256 + threadIdx.x;   // 2*16*256*32 = 262144 total
  int kk = id & 31;
  int np = (id >> 5) & 255;
  int ks = (id >> 13) & 15;
  int nb = id >> 17;
  int k = ks * 32 + kk, tap = k >> 8, kr = k & 255;
  int sel = np >> 7;                 // 0=value, 1=gate
  int f = nb * 128 + (np & 127);
  const float* W = sel ? Wg : Wv;
  wimg[id] = f2bf(W[((size_t)tap * 256 + kr) * 256 + f]);
  if (id < 512) bcat[id] = (id < 256) ? bv[id] : bg[id - 256];
}

// ---------------------------------------------------------------------------
// Main: 256 threads = 4 waves. Block = 64 time rows x one N-half (128 value +
// 128 gate cols). LDS = 40 KiB x-tile only -> 4 blocks/CU, 16 waves/CU.
// K-loop is BARRIER-FREE with register ping-pong weight prefetch (one step
// ahead). Transposed MFMA (weights in A-slot) -> float4 nt-stores.
// ---------------------------------------------------------------------------
__global__ __launch_bounds__(256, 4) void snail_main(
    const float* __restrict__ x, const short* __restrict__ wimg,
    const float* __restrict__ bcat, const int* __restrict__ dptr,
    float* __restrict__ out) {
  __shared__ __align__(16) short lx[NROWS * C_];   // 40 KiB, swizzled bf16 x-tile

  const int d = *dptr;
  // XCD-aware bijective swizzle (4096 blocks, 4096 % 8 == 0)
  const int bid = blockIdx.x;
  const int swz = (bid & 7) * 512 + (bid >> 3);
  const int nb = swz & 1;                 // N-half
  const int t0 = ((swz >> 1) & 63) * BM;  // time tile
  const int b  = swz >> 7;                // batch

  const int tid  = threadIdx.x;
  const int lane = tid & 63;
  const int w    = tid >> 6;
  const int row15 = lane & 15;
  const int qw    = lane >> 4;

  const float* xb = x + (size_t)b * T_ * C_;
  float* ob = out + (size_t)b * T_ * 512;

  // ---- stage x rows t0-d..t0+BM-1 into LDS (bf16, swizzled); fuse the exact
  //      fp32 passthrough for this block's N-half (x rows are in-register).
  for (int i = tid; i < d * 64; i += 256) {          // prefix rows [0,d)
    int r = i >> 6, c4 = i & 63;
    int t = t0 - d + r;
    f32x4 v = (f32x4){0.f, 0.f, 0.f, 0.f};
    if (t >= 0) v = *(const f32x4*)(xb + (size_t)t * C_ + c4 * 4);
    s16x4 s;
    s.x = f2bf(v.x); s.y = f2bf(v.y); s.z = f2bf(v.z); s.w = f2bf(v.w);
    int byte = (r * 512 + c4 * 8) ^ ((r & 7) << 4);
    *(s16x4*)((char*)lx + byte) = s;
  }
#pragma unroll 4
  for (int ii = 0; ii < 16; ++ii) {                  // main rows [d, d+BM)
    int i = ii * 256 + tid;
    int rr = i >> 6, c4 = i & 63;
    int t = t0 + rr, r = rr + d;
    f32x4 v = *(const f32x4*)(xb + (size_t)t * C_ + c4 * 4);
    if ((c4 >> 5) == nb)   // this block's half of the passthrough cols
      __builtin_nontemporal_store(v, (f32x4*)(ob + (size_t)t * 512 + C_ + c4 * 4));
    s16x4 s;
    s.x = f2bf(v.x); s.y = f2bf(v.y); s.z = f2bf(v.z); s.w = f2bf(v.w);
    int byte = (r * 512 + c4 * 8) ^ ((r & 7) << 4);
    *(s16x4*)((char*)lx + byte) = s;
  }
  __syncthreads();   // the ONLY barrier

  f32x4 accv[4][2], accg[4][2];
#pragma unroll
  for (int mi = 0; mi < 4; ++mi)
#pragma unroll
    for (int ni = 0; ni < 2; ++ni) {
      accv[mi][ni] = (f32x4){0.f, 0.f, 0.f, 0.f};
      accg[mi][ni] = (f32x4){0.f, 0.f, 0.f, 0.f};
    }

  // per-lane weight base: np = w*32 + row15 (value), kk = qw*8
  const short* wl = wimg + (size_t)nb * 131072 + (w * 32 + row15) * 32 + qw * 8;

#define LOADW(D0, D1, D2, D3, KS) do {                                  \
    const short* wk_ = wl + (KS) * 8192;                                \
    D0 = *(const bf16x8*)(wk_);                                         \
    D1 = *(const bf16x8*)(wk_ + 512);                                   \
    D2 = *(const bf16x8*)(wk_ + 4096);                                  \
    D3 = *(const bf16x8*)(wk_ + 4608);                                  \
  } while (0)

#define STEP(B0, B1, G0, G1, KS) do {                                   \
    bf16x8 af[4];                                                       \
    const int rofs_ = ((KS) >= 8) ? d : 0;                              \
    const int cb_ = ((KS) & 7) * 64 + qw * 16;                          \
    _Pragma("unroll")                                                   \
    for (int mi = 0; mi < 4; ++mi) {                                    \
      int r_ = 16 * mi + row15 + rofs_;                                 \
      af[mi] = *(const bf16x8*)((const char*)lx +                       \
               ((r_ * 512 + cb_) ^ ((r_ & 7) << 4)));                   \
    }                                                                   \
    _Pragma("unroll")                                                   \
    for (int mi = 0; mi < 4; ++mi) {                                    \
      accv[mi][0] = __builtin_amdgcn_mfma_f32_16x16x32_bf16(B0, af[mi], accv[mi][0], 0, 0, 0); \
      accv[mi][1] = __builtin_amdgcn_mfma_f32_16x16x32_bf16(B1, af[mi], accv[mi][1], 0, 0, 0); \
      accg[mi][0] = __builtin_amdgcn_mfma_f32_16x16x32_bf16(G0, af[mi], accg[mi][0], 0, 0, 0); \
      accg[mi][1] = __builtin_amdgcn_mfma_f32_16x16x32_bf16(G1, af[mi], accg[mi][1], 0, 0, 0); \
    }                                                                   \
  } while (0)

  bf16x8 a0, a1, a2, a3, b0, b1, b2, b3;
  LOADW(a0, a1, a2, a3, 0);
#pragma unroll 1
  for (int ks2 = 0; ks2 < 8; ++ks2) {
    LOADW(b0, b1, b2, b3, 2 * ks2 + 1);   // prefetch odd step
    STEP(a0, a1, a2, a3, 2 * ks2);        // compute even step (loads in flight)
    if (ks2 < 7) LOADW(a0, a1, a2, a3, 2 * ks2 + 2);  // prefetch next even
    STEP(b0, b1, b2, b3, 2 * ks2 + 1);    // compute odd step
  }
#undef LOADW
#undef STEP

  // ---- epilogue: out[t][f] = tanh(v+bv)*sigmoid(g+bg), float4 nt-stores
  //      D^T layout: t = t0+16mi+row15 ; f = nb*128 + w*32 + 16ni + qw*4 + j
#pragma unroll
  for (int ni = 0; ni < 2; ++ni) {
    int f0 = nb * 128 + w * 32 + 16 * ni + qw * 4;
    f32x4 bv4 = *(const f32x4*)(bcat + f0);
    f32x4 bg4 = *(const f32x4*)(bcat + 256 + f0);
#pragma unroll
    for (int mi = 0; mi < 4; ++mi) {
      int t = t0 + 16 * mi + row15;
      f32x4 v = accv[mi][ni], g = accg[mi][ni];
      f32x4 res;
#pragma unroll
      for (int j = 0; j < 4; ++j) {
        float vv = v[j] + bv4[j], gg = g[j] + bg4[j];
        float th = 1.f - 2.f * rcp_(__expf(2.f * vv) + 1.f);
        float sg = rcp_(1.f + __expf(-gg));
        res[j] = th * sg;
      }
      __builtin_nontemporal_store(res, (f32x4*)(ob + (size_t)t * 512 + f0));
    }
  }
}

extern "C" void kernel_launch(void* const* d_in, const int* in_sizes, int n_in,
                              void* d_out, int out_size, void* d_ws, size_t ws_size,
                              hipStream_t stream) {
  const float* x  = (const float*)d_in[0];
  const float* Wv = (const float*)d_in[1];
  const float* bv = (const float*)d_in[2];
  const float* Wg = (const float*)d_in[3];
  const float* bg = (const float*)d_in[4];
  const int* dil  = (const int*)d_in[5];
  float* out = (float*)d_out;

  short* wimg = (short*)d_ws;                          // 512 KiB weight image
  float* bcat = (float*)((char*)d_ws + 16 * 32768);    // 2 KiB biases

  prep_weights<<<1024, 256, 0, stream>>>(Wv, Wg, bv, bg, wimg, bcat);
  snail_main<<<B_ * (T_ / BM) * 2, 256, 0, stream>>>(x, wimg, bcat, dil, out);
}